// Round 5
// baseline (469.147 us; speedup 1.0000x reference)
//
#include <hip/hip_runtime.h>
#include <stdint.h>

#define NLEVELS 16
#define BLOCK 256

// ---------------- shared helpers ----------------

struct PointCtx {
    float nx, ny, nz;
    bool valid;
};

__device__ __forceinline__ PointCtx make_ctx(const float* __restrict__ xyz, int pt, int B,
                                             float mn0, float mn1, float mn2,
                                             float inv0, float inv1, float inv2)
{
    PointCtx P;
    P.nx = P.ny = P.nz = 0.0f;
    P.valid = false;
    if (pt < B) {
        const float x = xyz[3 * pt + 0];
        const float y = xyz[3 * pt + 1];
        const float z = xyz[3 * pt + 2];
        P.nx = (x - mn0) * inv0;
        P.ny = (y - mn1) * inv1;
        P.nz = (z - mn2) * inv2;
        P.valid = (P.nx >= 0.0f) && (P.nx <= 1.0f) &&
                  (P.ny >= 0.0f) && (P.ny <= 1.0f) &&
                  (P.nz >= 0.0f) && (P.nz <= 1.0f);
    }
    return P;
}

// Branchless trilinear hash-grid lookup: 8 fully independent float2 gathers,
// all addresses computed up-front so the scheduler can put every load in flight.
__device__ __forceinline__ float2 level_encode(const PointCtx& P,
                                               const float* __restrict__ emb,
                                               int l, int r)
{
    const float rm1 = (float)(r - 1);
    const float px = P.nx * rm1;
    const float py = P.ny * rm1;
    const float pz = P.nz * rm1;

    int fx = (int)floorf(px); fx = min(max(fx, 0), r - 2);
    int fy = (int)floorf(py); fy = min(max(fy, 0), r - 2);
    int fz = (int)floorf(pz); fz = min(max(fz, 0), r - 2);

    const float fracx = px - (float)fx;
    const float fracy = py - (float)fy;
    const float fracz = pz - (float)fz;

    const uint32_t hx0 = (uint32_t)fx;
    const uint32_t hx1 = hx0 + 1u;
    const uint32_t hy0 = (uint32_t)fy * 2654435761u;
    const uint32_t hy1 = hy0 + 2654435761u;
    const uint32_t hz0 = (uint32_t)fz * 805459861u;
    const uint32_t hz1 = hz0 + 805459861u;

    const float* __restrict__ lemb = emb + ((size_t)l << 20);  // l * 2^19 entries * 2

    float2 c[8];
    #pragma unroll
    for (int k = 0; k < 8; ++k) {
        const uint32_t h = ((k & 1) ? hx1 : hx0) ^
                           ((k & 2) ? hy1 : hy0) ^
                           ((k & 4) ? hz1 : hz0);
        c[k] = *reinterpret_cast<const float2*>(lemb + ((size_t)(h & 0x7FFFFu) << 1));
    }

    const float wx1 = fracx, wx0 = 1.0f - fracx;
    const float wy1 = fracy, wy0 = 1.0f - fracy;
    const float wz1 = fracz, wz0 = 1.0f - fracz;

    float acc0 = 0.0f, acc1 = 0.0f;
    #pragma unroll
    for (int k = 0; k < 8; ++k) {
        const float w = ((k & 1) ? wx1 : wx0) *
                        ((k & 2) ? wy1 : wy0) *
                        ((k & 4) ? wz1 : wz0);
        acc0 = fmaf(w, c[k].x, acc0);
        acc1 = fmaf(w, c[k].y, acc1);
    }
    float2 o;
    o.x = P.valid ? acc0 : 0.0f;
    o.y = P.valid ? acc1 : 0.0f;
    return o;
}

__device__ __forceinline__ void nt_store_f2(float2* p, float2 v)
{
    union { float2 f; unsigned long long u; } cvt;
    cvt.f = v;
    __builtin_nontemporal_store(cvt.u, reinterpret_cast<unsigned long long*>(p));
}

// ---------------- levels 0-4 fused (working set ~2.5 MB, L2-resident) ----------------
__global__ __launch_bounds__(BLOCK, 4) void level_gather_low_kernel(
    const float* __restrict__ xyz,
    const float* __restrict__ emb,
    const float* __restrict__ minv,
    const float* __restrict__ maxv,
    float2* __restrict__ ws2,
    int B)
{
    constexpr int RES[5] = {16, 22, 30, 42, 58};
    const int pt = blockIdx.x * BLOCK + threadIdx.x;
    if (pt >= B) return;

    const float mn0 = minv[0], mn1 = minv[1], mn2 = minv[2];
    const float inv0 = 1.0f / (maxv[0] - mn0);
    const float inv1 = 1.0f / (maxv[1] - mn1);
    const float inv2 = 1.0f / (maxv[2] - mn2);

    const PointCtx P = make_ctx(xyz, pt, B, mn0, mn1, mn2, inv0, inv1, inv2);

    float2 o[5];
    #pragma unroll
    for (int l = 0; l < 5; ++l) {
        o[l] = level_encode(P, emb, l, RES[l]);
    }
    #pragma unroll
    for (int l = 0; l < 5; ++l) {
        nt_store_f2(&ws2[(size_t)l * B + pt], o[l]);
    }
}

// ---------------- one level, 4 points per thread (levels 5-15) ----------------
#define NPT 4
template <int L, int R>
__global__ __launch_bounds__(BLOCK, 4) void level_gather_kernel(
    const float* __restrict__ xyz,
    const float* __restrict__ emb,
    const float* __restrict__ minv,
    const float* __restrict__ maxv,
    float2* __restrict__ ws2,
    int B)
{
    const int t = threadIdx.x;
    const int base = blockIdx.x * (NPT * BLOCK) + t;

    const float mn0 = minv[0], mn1 = minv[1], mn2 = minv[2];
    const float inv0 = 1.0f / (maxv[0] - mn0);
    const float inv1 = 1.0f / (maxv[1] - mn1);
    const float inv2 = 1.0f / (maxv[2] - mn2);

    PointCtx P[NPT];
    #pragma unroll
    for (int k = 0; k < NPT; ++k)
        P[k] = make_ctx(xyz, base + k * BLOCK, B, mn0, mn1, mn2, inv0, inv1, inv2);

    float2 o[NPT];
    #pragma unroll
    for (int k = 0; k < NPT; ++k)
        o[k] = level_encode(P[k], emb, L, R);

    #pragma unroll
    for (int k = 0; k < NPT; ++k)
        if (base + k * BLOCK < B)
            nt_store_f2(&ws2[(size_t)L * B + base + k * BLOCK], o[k]);
}

// ---------------- final transpose: ws[16][B][2] -> out[B][32] ----------------
__global__ __launch_bounds__(BLOCK) void transpose_kernel(
    const float2* __restrict__ ws2,
    float* __restrict__ out,
    int B)
{
    __shared__ float s[32][BLOCK + 1];   // stride 257: worst 2-way bank alias (free)
    const int t = threadIdx.x;
    const int pt = blockIdx.x * BLOCK + t;

    #pragma unroll
    for (int l = 0; l < NLEVELS; ++l) {
        union { unsigned long long u; float2 f; } cvt;
        cvt.f = make_float2(0.0f, 0.0f);
        if (pt < B)
            cvt.u = __builtin_nontemporal_load(
                reinterpret_cast<const unsigned long long*>(&ws2[(size_t)l * B + pt]));
        s[2 * l + 0][t] = cvt.f.x;
        s[2 * l + 1][t] = cvt.f.y;
    }
    __syncthreads();

    const size_t chunk = (size_t)blockIdx.x * (BLOCK * 32);
    const size_t total = (size_t)B * 32;
    #pragma unroll
    for (int k = 0; k < 32; ++k) {
        const int flat = k * BLOCK + t;
        const int p = flat >> 5;
        const int c = flat & 31;
        const size_t g = chunk + (size_t)flat;
        if (g < total) __builtin_nontemporal_store(s[c][p], &out[g]);
    }
}

// ---------------- fallback: single fused kernel (R0 structure) ----------------
__global__ __launch_bounds__(BLOCK) void hashgrid_fused_kernel(
    const float* __restrict__ xyz,
    const float* __restrict__ emb,
    const float* __restrict__ minv,
    const float* __restrict__ maxv,
    float* __restrict__ out,
    int B)
{
    constexpr int RES[NLEVELS] = {16, 22, 30, 42, 58, 80, 111, 154,
                                  212, 294, 406, 561, 776, 1072, 1482, 2048};
    __shared__ float s[32][BLOCK + 1];
    const int t = threadIdx.x;
    const int pt = blockIdx.x * BLOCK + t;

    const float mn0 = minv[0], mn1 = minv[1], mn2 = minv[2];
    const float inv0 = 1.0f / (maxv[0] - mn0);
    const float inv1 = 1.0f / (maxv[1] - mn1);
    const float inv2 = 1.0f / (maxv[2] - mn2);

    const PointCtx P = make_ctx(xyz, pt, B, mn0, mn1, mn2, inv0, inv1, inv2);

    #pragma unroll
    for (int l = 0; l < NLEVELS; ++l) {
        const float2 o = level_encode(P, emb, l, RES[l]);
        s[2 * l + 0][t] = o.x;
        s[2 * l + 1][t] = o.y;
    }
    __syncthreads();
    const size_t chunk = (size_t)blockIdx.x * (BLOCK * 32);
    const size_t total = (size_t)B * 32;
    #pragma unroll
    for (int k = 0; k < 32; ++k) {
        const int flat = k * BLOCK + t;
        const int p = flat >> 5;
        const int c = flat & 31;
        const size_t g = chunk + (size_t)flat;
        if (g < total) out[g] = s[c][p];
    }
}

extern "C" void kernel_launch(void* const* d_in, const int* in_sizes, int n_in,
                              void* d_out, int out_size, void* d_ws, size_t ws_size,
                              hipStream_t stream) {
    const float* xyz = (const float*)d_in[0];
    const float* emb = (const float*)d_in[1];
    const float* mn  = (const float*)d_in[2];
    const float* mx  = (const float*)d_in[3];
    float* out = (float*)d_out;

    const int B = in_sizes[0] / 3;
    const int blocks1 = (B + BLOCK - 1) / BLOCK;
    const int blocksN = (B + NPT * BLOCK - 1) / (NPT * BLOCK);
    const size_t ws_needed = (size_t)NLEVELS * (size_t)B * 2 * sizeof(float);

    if (ws_size >= ws_needed) {
        float2* ws2 = (float2*)d_ws;
        hipLaunchKernelGGL(level_gather_low_kernel, dim3(blocks1), dim3(BLOCK), 0, stream,
                           xyz, emb, mn, mx, ws2, B);
        #define LVL(L, R) hipLaunchKernelGGL((level_gather_kernel<L, R>), dim3(blocksN), dim3(BLOCK), 0, stream, xyz, emb, mn, mx, ws2, B)
        LVL(5, 80);  LVL(6, 111);  LVL(7, 154);  LVL(8, 212);
        LVL(9, 294); LVL(10, 406); LVL(11, 561); LVL(12, 776);
        LVL(13, 1072); LVL(14, 1482); LVL(15, 2048);
        #undef LVL
        hipLaunchKernelGGL(transpose_kernel, dim3(blocks1), dim3(BLOCK), 0, stream,
                           ws2, out, B);
    } else {
        hipLaunchKernelGGL(hashgrid_fused_kernel, dim3(blocks1), dim3(BLOCK), 0, stream,
                           xyz, emb, mn, mx, out, B);
    }
}

// Round 6
// 401.209 us; speedup vs baseline: 1.1693x; 1.1693x over previous
//
#include <hip/hip_runtime.h>
#include <hip/hip_fp16.h>
#include <stdint.h>

#define NLEVELS 16
#define BLOCK 256
#define NPT 2

// ws layout: [0, 32MiB) f16 table copy; [32MiB, +64MB) per-level half2 slabs
#define TAB16_HALVES (16777216u)             // 8,388,608 entries * 2
#define TAB16_BYTES  ((size_t)TAB16_HALVES * 2)   // 32 MiB

// ---------------- f32 -> f16 table convert (one-time per launch) ----------------
__global__ __launch_bounds__(BLOCK) void convert_kernel(
    const float* __restrict__ emb, __half* __restrict__ tab)
{
    const int n4 = TAB16_HALVES / 4;   // float4 chunks
    for (int i = blockIdx.x * BLOCK + threadIdx.x; i < n4; i += gridDim.x * BLOCK) {
        const float4 v = *reinterpret_cast<const float4*>(emb + 4 * (size_t)i);
        __half2 a = __floats2half2_rn(v.x, v.y);
        __half2 b = __floats2half2_rn(v.z, v.w);
        uint2 packed;
        packed.x = *reinterpret_cast<uint32_t*>(&a);
        packed.y = *reinterpret_cast<uint32_t*>(&b);
        __builtin_nontemporal_store(packed.x, reinterpret_cast<uint32_t*>(tab + 4 * (size_t)i));
        __builtin_nontemporal_store(packed.y, reinterpret_cast<uint32_t*>(tab + 4 * (size_t)i) + 1);
    }
}

// ---------------- shared helpers ----------------
struct PointCtx {
    float nx, ny, nz;
    bool valid;
};

__device__ __forceinline__ PointCtx make_ctx(const float* __restrict__ xyz, int pt, int B,
                                             float mn0, float mn1, float mn2,
                                             float inv0, float inv1, float inv2)
{
    PointCtx P;
    P.nx = P.ny = P.nz = 0.0f;
    P.valid = false;
    if (pt < B) {
        const float x = xyz[3 * pt + 0];
        const float y = xyz[3 * pt + 1];
        const float z = xyz[3 * pt + 2];
        P.nx = (x - mn0) * inv0;
        P.ny = (y - mn1) * inv1;
        P.nz = (z - mn2) * inv2;
        P.valid = (P.nx >= 0.0f) && (P.nx <= 1.0f) &&
                  (P.ny >= 0.0f) && (P.ny <= 1.0f) &&
                  (P.nz >= 0.0f) && (P.nz <= 1.0f);
    }
    return P;
}

// f16-table trilinear lookup with x-corner pairing:
// primes[0]==1 -> for even fx, corners (fx,fx+1) hash to {i, i^1}: one aligned
// 8B load covers both. Odd-fx lanes issue one extra exec-masked 4B load.
__device__ __forceinline__ float2 level_encode16(const PointCtx& P,
                                                 const __half* __restrict__ tab,
                                                 int l, int r)
{
    const float rm1 = (float)(r - 1);
    const float px = P.nx * rm1;
    const float py = P.ny * rm1;
    const float pz = P.nz * rm1;

    int fx = (int)floorf(px); fx = min(max(fx, 0), r - 2);
    int fy = (int)floorf(py); fy = min(max(fy, 0), r - 2);
    int fz = (int)floorf(pz); fz = min(max(fz, 0), r - 2);

    const float fracx = px - (float)fx;
    const float fracy = py - (float)fy;
    const float fracz = pz - (float)fz;

    const uint32_t hx0 = (uint32_t)fx;
    const uint32_t hy0 = (uint32_t)fy * 2654435761u;
    const uint32_t hy1 = hy0 + 2654435761u;
    const uint32_t hz0 = (uint32_t)fz * 805459861u;
    const uint32_t hz1 = hz0 + 805459861u;
    const bool oddx = (fx & 1) != 0;

    const __half* __restrict__ lt = tab + ((size_t)l << 20);  // 2^19 entries * 2 halves

    const float wx1 = fracx, wx0 = 1.0f - fracx;
    const float wy1 = fracy, wy0 = 1.0f - fracy;
    const float wz1 = fracz, wz0 = 1.0f - fracz;

    float acc0 = 0.0f, acc1 = 0.0f;
    #pragma unroll
    for (int yz = 0; yz < 4; ++yz) {
        const uint32_t rest = ((yz & 1) ? hy1 : hy0) ^ ((yz & 2) ? hz1 : hz0);
        const float wyz = ((yz & 1) ? wy1 : wy0) * ((yz & 2) ? wz1 : wz0);
        const uint32_t i0 = (hx0 ^ rest) & 0x7FFFFu;          // corner (fx)

        // 8B load covering entries {i0&~1, i0|1}
        const uint2 pair = *reinterpret_cast<const uint2*>(lt + ((size_t)(i0 & ~1u) << 1));
        const uint32_t lo = pair.x, hi = pair.y;
        const uint32_t e0 = (i0 & 1u) ? hi : lo;              // corner fx
        uint32_t e1;
        if (oddx) {                                           // exec-masked extra load
            const uint32_t i1 = ((hx0 + 1u) ^ rest) & 0x7FFFFu;
            e1 = *reinterpret_cast<const uint32_t*>(lt + ((size_t)i1 << 1));
        } else {
            e1 = (i0 & 1u) ? lo : hi;                         // corner fx+1 = i0^1
        }
        const float2 c0 = __half22float2(*reinterpret_cast<const __half2*>(&e0));
        const float2 c1 = __half22float2(*reinterpret_cast<const __half2*>(&e1));
        acc0 += wyz * (wx0 * c0.x + wx1 * c1.x);
        acc1 += wyz * (wx0 * c0.y + wx1 * c1.y);
    }
    float2 o;
    o.x = P.valid ? acc0 : 0.0f;
    o.y = P.valid ? acc1 : 0.0f;
    return o;
}

__device__ __forceinline__ void nt_store_h2(__half2* p, float2 v)
{
    __half2 h = __floats2half2_rn(v.x, v.y);
    __builtin_nontemporal_store(*reinterpret_cast<uint32_t*>(&h),
                                reinterpret_cast<uint32_t*>(p));
}

// ---------------- levels 0-4 fused (f16 working set ~1.25 MB) ----------------
__global__ __launch_bounds__(BLOCK) void level_gather_low_kernel(
    const float* __restrict__ xyz,
    const __half* __restrict__ tab,
    const float* __restrict__ minv,
    const float* __restrict__ maxv,
    __half2* __restrict__ wsh,
    int B)
{
    constexpr int RES[5] = {16, 22, 30, 42, 58};
    const int pt = blockIdx.x * BLOCK + threadIdx.x;
    if (pt >= B) return;

    const float mn0 = minv[0], mn1 = minv[1], mn2 = minv[2];
    const float inv0 = 1.0f / (maxv[0] - mn0);
    const float inv1 = 1.0f / (maxv[1] - mn1);
    const float inv2 = 1.0f / (maxv[2] - mn2);

    const PointCtx P = make_ctx(xyz, pt, B, mn0, mn1, mn2, inv0, inv1, inv2);

    #pragma unroll
    for (int l = 0; l < 5; ++l) {
        nt_store_h2(&wsh[(size_t)l * B + pt], level_encode16(P, tab, l, RES[l]));
    }
}

// ---------------- one level, 2 points per thread (levels 5-15) ----------------
template <int L, int R>
__global__ __launch_bounds__(BLOCK, 6) void level_gather_kernel(
    const float* __restrict__ xyz,
    const __half* __restrict__ tab,
    const float* __restrict__ minv,
    const float* __restrict__ maxv,
    __half2* __restrict__ wsh,
    int B)
{
    const int t = threadIdx.x;
    const int base = blockIdx.x * (NPT * BLOCK) + t;

    const float mn0 = minv[0], mn1 = minv[1], mn2 = minv[2];
    const float inv0 = 1.0f / (maxv[0] - mn0);
    const float inv1 = 1.0f / (maxv[1] - mn1);
    const float inv2 = 1.0f / (maxv[2] - mn2);

    PointCtx P[NPT];
    #pragma unroll
    for (int k = 0; k < NPT; ++k)
        P[k] = make_ctx(xyz, base + k * BLOCK, B, mn0, mn1, mn2, inv0, inv1, inv2);

    float2 o[NPT];
    #pragma unroll
    for (int k = 0; k < NPT; ++k)
        o[k] = level_encode16(P[k], tab, L, R);

    #pragma unroll
    for (int k = 0; k < NPT; ++k)
        if (base + k * BLOCK < B)
            nt_store_h2(&wsh[(size_t)L * B + base + k * BLOCK], o[k]);
}

// ---------------- final transpose: wsh[16][B] (half2) -> out[B][32] (f32) ----------------
__global__ __launch_bounds__(BLOCK) void transpose_kernel(
    const __half2* __restrict__ wsh,
    float* __restrict__ out,
    int B)
{
    __shared__ float s[32][BLOCK + 1];   // stride 257: worst 2-way bank alias (free)
    const int t = threadIdx.x;
    const int pt = blockIdx.x * BLOCK + t;

    #pragma unroll
    for (int l = 0; l < NLEVELS; ++l) {
        float2 v = make_float2(0.0f, 0.0f);
        if (pt < B) {
            const uint32_t bits = __builtin_nontemporal_load(
                reinterpret_cast<const uint32_t*>(&wsh[(size_t)l * B + pt]));
            v = __half22float2(*reinterpret_cast<const __half2*>(&bits));
        }
        s[2 * l + 0][t] = v.x;
        s[2 * l + 1][t] = v.y;
    }
    __syncthreads();

    const size_t chunk = (size_t)blockIdx.x * (BLOCK * 32);
    const size_t total = (size_t)B * 32;
    #pragma unroll
    for (int k = 0; k < 32; ++k) {
        const int flat = k * BLOCK + t;
        const int p = flat >> 5;
        const int c = flat & 31;
        const size_t g = chunk + (size_t)flat;
        if (g < total) __builtin_nontemporal_store(s[c][p], &out[g]);
    }
}

// ---------------- fallback: single fused f32 kernel ----------------
__device__ __forceinline__ float2 level_encode32(const PointCtx& P,
                                                 const float* __restrict__ emb,
                                                 int l, int r)
{
    const float rm1 = (float)(r - 1);
    const float px = P.nx * rm1, py = P.ny * rm1, pz = P.nz * rm1;
    int fx = (int)floorf(px); fx = min(max(fx, 0), r - 2);
    int fy = (int)floorf(py); fy = min(max(fy, 0), r - 2);
    int fz = (int)floorf(pz); fz = min(max(fz, 0), r - 2);
    const float fracx = px - (float)fx;
    const float fracy = py - (float)fy;
    const float fracz = pz - (float)fz;
    const uint32_t hx0 = (uint32_t)fx, hx1 = hx0 + 1u;
    const uint32_t hy0 = (uint32_t)fy * 2654435761u, hy1 = hy0 + 2654435761u;
    const uint32_t hz0 = (uint32_t)fz * 805459861u,  hz1 = hz0 + 805459861u;
    const float* __restrict__ lemb = emb + ((size_t)l << 20);
    float2 c[8];
    #pragma unroll
    for (int k = 0; k < 8; ++k) {
        const uint32_t h = ((k & 1) ? hx1 : hx0) ^
                           ((k & 2) ? hy1 : hy0) ^
                           ((k & 4) ? hz1 : hz0);
        c[k] = *reinterpret_cast<const float2*>(lemb + ((size_t)(h & 0x7FFFFu) << 1));
    }
    const float wx1 = fracx, wx0 = 1.0f - fracx;
    const float wy1 = fracy, wy0 = 1.0f - fracy;
    const float wz1 = fracz, wz0 = 1.0f - fracz;
    float acc0 = 0.0f, acc1 = 0.0f;
    #pragma unroll
    for (int k = 0; k < 8; ++k) {
        const float w = ((k & 1) ? wx1 : wx0) *
                        ((k & 2) ? wy1 : wy0) *
                        ((k & 4) ? wz1 : wz0);
        acc0 = fmaf(w, c[k].x, acc0);
        acc1 = fmaf(w, c[k].y, acc1);
    }
    float2 o;
    o.x = P.valid ? acc0 : 0.0f;
    o.y = P.valid ? acc1 : 0.0f;
    return o;
}

__global__ __launch_bounds__(BLOCK) void hashgrid_fused_kernel(
    const float* __restrict__ xyz,
    const float* __restrict__ emb,
    const float* __restrict__ minv,
    const float* __restrict__ maxv,
    float* __restrict__ out,
    int B)
{
    constexpr int RES[NLEVELS] = {16, 22, 30, 42, 58, 80, 111, 154,
                                  212, 294, 406, 561, 776, 1072, 1482, 2048};
    __shared__ float s[32][BLOCK + 1];
    const int t = threadIdx.x;
    const int pt = blockIdx.x * BLOCK + t;

    const float mn0 = minv[0], mn1 = minv[1], mn2 = minv[2];
    const float inv0 = 1.0f / (maxv[0] - mn0);
    const float inv1 = 1.0f / (maxv[1] - mn1);
    const float inv2 = 1.0f / (maxv[2] - mn2);

    const PointCtx P = make_ctx(xyz, pt, B, mn0, mn1, mn2, inv0, inv1, inv2);

    #pragma unroll
    for (int l = 0; l < NLEVELS; ++l) {
        const float2 o = level_encode32(P, emb, l, RES[l]);
        s[2 * l + 0][t] = o.x;
        s[2 * l + 1][t] = o.y;
    }
    __syncthreads();
    const size_t chunk = (size_t)blockIdx.x * (BLOCK * 32);
    const size_t total = (size_t)B * 32;
    #pragma unroll
    for (int k = 0; k < 32; ++k) {
        const int flat = k * BLOCK + t;
        const int p = flat >> 5;
        const int c = flat & 31;
        const size_t g = chunk + (size_t)flat;
        if (g < total) out[g] = s[c][p];
    }
}

extern "C" void kernel_launch(void* const* d_in, const int* in_sizes, int n_in,
                              void* d_out, int out_size, void* d_ws, size_t ws_size,
                              hipStream_t stream) {
    const float* xyz = (const float*)d_in[0];
    const float* emb = (const float*)d_in[1];
    const float* mn  = (const float*)d_in[2];
    const float* mx  = (const float*)d_in[3];
    float* out = (float*)d_out;

    const int B = in_sizes[0] / 3;
    const int blocks1 = (B + BLOCK - 1) / BLOCK;
    const int blocksN = (B + NPT * BLOCK - 1) / (NPT * BLOCK);
    const size_t ws_needed = TAB16_BYTES + (size_t)NLEVELS * (size_t)B * sizeof(__half2);

    if (ws_size >= ws_needed) {
        __half* tab = (__half*)d_ws;
        __half2* wsh = (__half2*)((char*)d_ws + TAB16_BYTES);

        hipLaunchKernelGGL(convert_kernel, dim3(2048), dim3(BLOCK), 0, stream, emb, tab);

        hipLaunchKernelGGL(level_gather_low_kernel, dim3(blocks1), dim3(BLOCK), 0, stream,
                           xyz, tab, mn, mx, wsh, B);
        #define LVL(L, R) hipLaunchKernelGGL((level_gather_kernel<L, R>), dim3(blocksN), dim3(BLOCK), 0, stream, xyz, tab, mn, mx, wsh, B)
        LVL(5, 80);  LVL(6, 111);  LVL(7, 154);  LVL(8, 212);
        LVL(9, 294); LVL(10, 406); LVL(11, 561); LVL(12, 776);
        LVL(13, 1072); LVL(14, 1482); LVL(15, 2048);
        #undef LVL
        hipLaunchKernelGGL(transpose_kernel, dim3(blocks1), dim3(BLOCK), 0, stream,
                           wsh, out, B);
    } else {
        hipLaunchKernelGGL(hashgrid_fused_kernel, dim3(blocks1), dim3(BLOCK), 0, stream,
                           xyz, emb, mn, mx, out, B);
    }
}

// Round 7
// 387.594 us; speedup vs baseline: 1.2104x; 1.0351x over previous
//
#include <hip/hip_runtime.h>
#include <hip/hip_fp16.h>
#include <stdint.h>

#define NLEVELS 16
#define BLOCK 256
#define NPT 2

#define P1 2654435761u
#define P2 805459861u
#define HMASK 0x7FFFFu

// dense tables for levels 0..5 (r^3 <= 2^19): entry = f16x2 packed in u32
__device__ __host__ constexpr int DRES(int l) {
    constexpr int r[6] = {16, 22, 30, 42, 58, 80};
    return r[l];
}
__device__ __host__ constexpr uint32_t DOFF(int l) {
    constexpr uint32_t o[6] = {0, 4096, 14744, 41744, 115832, 310944};
    return o[l];
}
#define DENSE_ENTRIES 822944u                       // sum of r^3, l=0..5
#define HASH16_ENTRIES (10u << 19)                  // levels 6..15
#define HASH16_BYTES ((size_t)HASH16_ENTRIES * 4)
#define DENSE_BYTES  ((size_t)DENSE_ENTRIES * 4)

// ---------------- one-time table prep ----------------

// f32 hash table levels 6..15 -> f16x2 copy
__global__ __launch_bounds__(BLOCK) void convert_hash_kernel(
    const float* __restrict__ emb, uint32_t* __restrict__ tab16)
{
    const uint32_t i = blockIdx.x * BLOCK + threadIdx.x;
    if (i >= HASH16_ENTRIES) return;
    const float2 v = *reinterpret_cast<const float2*>(
        emb + (((size_t)(6u << 19)) + i) * 2);
    __half2 hv = __floats2half2_rn(v.x, v.y);
    __builtin_nontemporal_store(*reinterpret_cast<uint32_t*>(&hv), &tab16[i]);
}

// dense re-index for one low level: dense[x + y*r + z*r^2] = emb[hash(x,y,z)]
template <int LIDX>
__global__ __launch_bounds__(BLOCK) void dense_build_kernel(
    const float* __restrict__ emb, uint32_t* __restrict__ dense)
{
    constexpr int r = DRES(LIDX);
    constexpr uint32_t off = DOFF(LIDX);
    const int n = r * r * r;
    const int i = blockIdx.x * BLOCK + threadIdx.x;
    if (i >= n) return;
    const int z = i / (r * r);
    const int rem = i - z * (r * r);
    const int y = rem / r;
    const int x = rem - y * r;
    const uint32_t h = ((uint32_t)x ^ ((uint32_t)y * P1) ^ ((uint32_t)z * P2)) & HMASK;
    const float2 v = *reinterpret_cast<const float2*>(
        emb + (((size_t)LIDX << 19) + h) * 2);
    __half2 hv = __floats2half2_rn(v.x, v.y);
    dense[off + i] = *reinterpret_cast<uint32_t*>(&hv);
}

// ---------------- shared helpers ----------------

struct PointCtx { float nx, ny, nz; bool valid; };

__device__ __forceinline__ PointCtx make_ctx(const float* __restrict__ xyz, int pt, int B,
                                             float mn0, float mn1, float mn2,
                                             float inv0, float inv1, float inv2)
{
    PointCtx P;
    P.nx = P.ny = P.nz = 0.0f;
    P.valid = false;
    if (pt < B) {
        const float x = xyz[3 * pt + 0];
        const float y = xyz[3 * pt + 1];
        const float z = xyz[3 * pt + 2];
        P.nx = (x - mn0) * inv0;
        P.ny = (y - mn1) * inv1;
        P.nz = (z - mn2) * inv2;
        P.valid = (P.nx >= 0.0f) && (P.nx <= 1.0f) &&
                  (P.ny >= 0.0f) && (P.ny <= 1.0f) &&
                  (P.nz >= 0.0f) && (P.nz <= 1.0f);
    }
    return P;
}

struct C8 { uint32_t idx[8]; float w[8]; };

__device__ __forceinline__ void frac_setup(const PointCtx& P, int r,
                                           int& fx, int& fy, int& fz,
                                           float& wx0, float& wx1,
                                           float& wy0, float& wy1,
                                           float& wz0, float& wz1)
{
    const float rm1 = (float)(r - 1);
    const float px = P.nx * rm1, py = P.ny * rm1, pz = P.nz * rm1;
    fx = (int)floorf(px); fx = min(max(fx, 0), r - 2);
    fy = (int)floorf(py); fy = min(max(fy, 0), r - 2);
    fz = (int)floorf(pz); fz = min(max(fz, 0), r - 2);
    wx1 = px - (float)fx; wx0 = 1.0f - wx1;
    wy1 = py - (float)fy; wy0 = 1.0f - wy1;
    wz1 = pz - (float)fz; wz0 = 1.0f - wz1;
}

__device__ __forceinline__ C8 mk_hash(const PointCtx& P, int r)
{
    int fx, fy, fz; float wx0, wx1, wy0, wy1, wz0, wz1;
    frac_setup(P, r, fx, fy, fz, wx0, wx1, wy0, wy1, wz0, wz1);
    const uint32_t hx0 = (uint32_t)fx,        hx1 = hx0 + 1u;
    const uint32_t hy0 = (uint32_t)fy * P1,   hy1 = hy0 + P1;
    const uint32_t hz0 = (uint32_t)fz * P2,   hz1 = hz0 + P2;
    C8 c;
    #pragma unroll
    for (int k = 0; k < 8; ++k) {
        c.idx[k] = (((k & 1) ? hx1 : hx0) ^
                    ((k & 2) ? hy1 : hy0) ^
                    ((k & 4) ? hz1 : hz0)) & HMASK;
        c.w[k] = ((k & 1) ? wx1 : wx0) * ((k & 2) ? wy1 : wy0) * ((k & 4) ? wz1 : wz0);
    }
    return c;
}

__device__ __forceinline__ C8 mk_dense(const PointCtx& P, int r, uint32_t off)
{
    int fx, fy, fz; float wx0, wx1, wy0, wy1, wz0, wz1;
    frac_setup(P, r, fx, fy, fz, wx0, wx1, wy0, wy1, wz0, wz1);
    const uint32_t base = off + (uint32_t)(fx + fy * r + fz * r * r);
    C8 c;
    #pragma unroll
    for (int k = 0; k < 8; ++k) {
        c.idx[k] = base + (uint32_t)((k & 1) + ((k & 2) ? r : 0) + ((k & 4) ? r * r : 0));
        c.w[k] = ((k & 1) ? wx1 : wx0) * ((k & 2) ? wy1 : wy0) * ((k & 4) ? wz1 : wz0);
    }
    return c;
}

__device__ __forceinline__ float2 accum8(const C8& c, const uint32_t* e, bool valid)
{
    float a = 0.0f, b = 0.0f;
    #pragma unroll
    for (int k = 0; k < 8; ++k) {
        const float2 f = __half22float2(*reinterpret_cast<const __half2*>(&e[k]));
        a = fmaf(c.w[k], f.x, a);
        b = fmaf(c.w[k], f.y, b);
    }
    float2 o;
    o.x = valid ? a : 0.0f;
    o.y = valid ? b : 0.0f;
    return o;
}

__device__ __forceinline__ void nt_store_f2h(uint32_t* p, float2 v)
{
    __half2 h = __floats2half2_rn(v.x, v.y);
    __builtin_nontemporal_store(*reinterpret_cast<uint32_t*>(&h), p);
}

// ---------------- levels 0-4 (dense tables, L1/L2-resident) ----------------
__global__ __launch_bounds__(BLOCK, 4) void dense_low_kernel(
    const float* __restrict__ xyz,
    const uint32_t* __restrict__ dense,
    const float* __restrict__ minv,
    const float* __restrict__ maxv,
    uint32_t* __restrict__ slab,
    int B)
{
    const int t = threadIdx.x;
    const int p0 = blockIdx.x * (NPT * BLOCK) + t;
    const int p1 = p0 + BLOCK;

    const float mn0 = minv[0], mn1 = minv[1], mn2 = minv[2];
    const float inv0 = 1.0f / (maxv[0] - mn0);
    const float inv1 = 1.0f / (maxv[1] - mn1);
    const float inv2 = 1.0f / (maxv[2] - mn2);

    const PointCtx A = make_ctx(xyz, p0, B, mn0, mn1, mn2, inv0, inv1, inv2);
    const PointCtx Bc = make_ctx(xyz, p1, B, mn0, mn1, mn2, inv0, inv1, inv2);

    #pragma unroll
    for (int l = 0; l < 5; ++l) {
        const C8 c0 = mk_dense(A,  DRES(l), DOFF(l));
        const C8 c1 = mk_dense(Bc, DRES(l), DOFF(l));
        uint32_t e0[8], e1[8];
        #pragma unroll
        for (int k = 0; k < 8; ++k) e0[k] = dense[c0.idx[k]];
        #pragma unroll
        for (int k = 0; k < 8; ++k) e1[k] = dense[c1.idx[k]];
        const float2 o0 = accum8(c0, e0, A.valid);
        const float2 o1 = accum8(c1, e1, Bc.valid);
        if (p0 < B) nt_store_f2h(&slab[(size_t)l * B + p0], o0);
        if (p1 < B) nt_store_f2h(&slab[(size_t)l * B + p1], o1);
    }
}

// ---------------- level 5 (dense, 2 MB table ~ one XCD L2) ----------------
__global__ __launch_bounds__(BLOCK, 4) void dense_l5_kernel(
    const float* __restrict__ xyz,
    const uint32_t* __restrict__ dense,
    const float* __restrict__ minv,
    const float* __restrict__ maxv,
    uint32_t* __restrict__ slab,
    int B)
{
    const int t = threadIdx.x;
    const int p0 = blockIdx.x * (NPT * BLOCK) + t;
    const int p1 = p0 + BLOCK;

    const float mn0 = minv[0], mn1 = minv[1], mn2 = minv[2];
    const float inv0 = 1.0f / (maxv[0] - mn0);
    const float inv1 = 1.0f / (maxv[1] - mn1);
    const float inv2 = 1.0f / (maxv[2] - mn2);

    const PointCtx A = make_ctx(xyz, p0, B, mn0, mn1, mn2, inv0, inv1, inv2);
    const PointCtx Bc = make_ctx(xyz, p1, B, mn0, mn1, mn2, inv0, inv1, inv2);

    const C8 c0 = mk_dense(A,  DRES(5), DOFF(5));
    const C8 c1 = mk_dense(Bc, DRES(5), DOFF(5));
    uint32_t e0[8], e1[8];
    #pragma unroll
    for (int k = 0; k < 8; ++k) e0[k] = dense[c0.idx[k]];
    #pragma unroll
    for (int k = 0; k < 8; ++k) e1[k] = dense[c1.idx[k]];
    __builtin_amdgcn_sched_barrier(0);
    const float2 o0 = accum8(c0, e0, A.valid);
    const float2 o1 = accum8(c1, e1, Bc.valid);
    if (p0 < B) nt_store_f2h(&slab[(size_t)5 * B + p0], o0);
    if (p1 < B) nt_store_f2h(&slab[(size_t)5 * B + p1], o1);
}

// ---------------- hash levels 6-15, one per dispatch ----------------
template <int L, int R>
__global__ __launch_bounds__(BLOCK, 4) void hash_level_kernel(
    const float* __restrict__ xyz,
    const uint32_t* __restrict__ tab16,
    const float* __restrict__ minv,
    const float* __restrict__ maxv,
    uint32_t* __restrict__ slab,
    int B)
{
    const uint32_t* __restrict__ lt = tab16 + ((size_t)(L - 6) << 19);
    const int t = threadIdx.x;
    const int p0 = blockIdx.x * (NPT * BLOCK) + t;
    const int p1 = p0 + BLOCK;

    const float mn0 = minv[0], mn1 = minv[1], mn2 = minv[2];
    const float inv0 = 1.0f / (maxv[0] - mn0);
    const float inv1 = 1.0f / (maxv[1] - mn1);
    const float inv2 = 1.0f / (maxv[2] - mn2);

    const PointCtx A = make_ctx(xyz, p0, B, mn0, mn1, mn2, inv0, inv1, inv2);
    const PointCtx Bc = make_ctx(xyz, p1, B, mn0, mn1, mn2, inv0, inv1, inv2);

    const C8 c0 = mk_hash(A,  R);
    const C8 c1 = mk_hash(Bc, R);
    uint32_t e0[8], e1[8];
    #pragma unroll
    for (int k = 0; k < 8; ++k) e0[k] = lt[c0.idx[k]];
    #pragma unroll
    for (int k = 0; k < 8; ++k) e1[k] = lt[c1.idx[k]];
    __builtin_amdgcn_sched_barrier(0);
    const float2 o0 = accum8(c0, e0, A.valid);
    const float2 o1 = accum8(c1, e1, Bc.valid);
    if (p0 < B) nt_store_f2h(&slab[(size_t)L * B + p0], o0);
    if (p1 < B) nt_store_f2h(&slab[(size_t)L * B + p1], o1);
}

// ---------------- final transpose: slab[16][B] (f16x2) -> out[B][32] (f32) ----------------
__global__ __launch_bounds__(BLOCK) void transpose_kernel(
    const uint32_t* __restrict__ slab,
    float* __restrict__ out,
    int B)
{
    __shared__ float s[32][BLOCK + 1];
    const int t = threadIdx.x;
    const int pt = blockIdx.x * BLOCK + t;

    #pragma unroll
    for (int l = 0; l < NLEVELS; ++l) {
        float2 v = make_float2(0.0f, 0.0f);
        if (pt < B) {
            const uint32_t bits = __builtin_nontemporal_load(&slab[(size_t)l * B + pt]);
            v = __half22float2(*reinterpret_cast<const __half2*>(&bits));
        }
        s[2 * l + 0][t] = v.x;
        s[2 * l + 1][t] = v.y;
    }
    __syncthreads();

    const size_t chunk = (size_t)blockIdx.x * (BLOCK * 32);
    const size_t total = (size_t)B * 32;
    #pragma unroll
    for (int k = 0; k < 32; ++k) {
        const int flat = k * BLOCK + t;
        const int p = flat >> 5;
        const int c = flat & 31;
        const size_t g = chunk + (size_t)flat;
        if (g < total) __builtin_nontemporal_store(s[c][p], &out[g]);
    }
}

// ---------------- fallback: single fused f32 kernel ----------------
__global__ __launch_bounds__(BLOCK) void hashgrid_fused_kernel(
    const float* __restrict__ xyz,
    const float* __restrict__ emb,
    const float* __restrict__ minv,
    const float* __restrict__ maxv,
    float* __restrict__ out,
    int B)
{
    constexpr int RES[NLEVELS] = {16, 22, 30, 42, 58, 80, 111, 154,
                                  212, 294, 406, 561, 776, 1072, 1482, 2048};
    __shared__ float s[32][BLOCK + 1];
    const int t = threadIdx.x;
    const int pt = blockIdx.x * BLOCK + t;

    const float mn0 = minv[0], mn1 = minv[1], mn2 = minv[2];
    const float inv0 = 1.0f / (maxv[0] - mn0);
    const float inv1 = 1.0f / (maxv[1] - mn1);
    const float inv2 = 1.0f / (maxv[2] - mn2);

    const PointCtx P = make_ctx(xyz, pt, B, mn0, mn1, mn2, inv0, inv1, inv2);

    #pragma unroll
    for (int l = 0; l < NLEVELS; ++l) {
        const C8 c = mk_hash(P, RES[l]);
        const float* __restrict__ lemb = emb + ((size_t)l << 20);
        float acc0 = 0.0f, acc1 = 0.0f;
        #pragma unroll
        for (int k = 0; k < 8; ++k) {
            const float2 f = *reinterpret_cast<const float2*>(
                lemb + ((size_t)c.idx[k] << 1));
            acc0 = fmaf(c.w[k], f.x, acc0);
            acc1 = fmaf(c.w[k], f.y, acc1);
        }
        s[2 * l + 0][t] = P.valid ? acc0 : 0.0f;
        s[2 * l + 1][t] = P.valid ? acc1 : 0.0f;
    }
    __syncthreads();
    const size_t chunk = (size_t)blockIdx.x * (BLOCK * 32);
    const size_t total = (size_t)B * 32;
    #pragma unroll
    for (int k = 0; k < 32; ++k) {
        const int flat = k * BLOCK + t;
        const int p = flat >> 5;
        const int c = flat & 31;
        const size_t g = chunk + (size_t)flat;
        if (g < total) out[g] = s[c][p];
    }
}

extern "C" void kernel_launch(void* const* d_in, const int* in_sizes, int n_in,
                              void* d_out, int out_size, void* d_ws, size_t ws_size,
                              hipStream_t stream) {
    const float* xyz = (const float*)d_in[0];
    const float* emb = (const float*)d_in[1];
    const float* mn  = (const float*)d_in[2];
    const float* mx  = (const float*)d_in[3];
    float* out = (float*)d_out;

    const int B = in_sizes[0] / 3;
    const int blocks1 = (B + BLOCK - 1) / BLOCK;
    const int blocks2 = (B + NPT * BLOCK - 1) / (NPT * BLOCK);

    const size_t slab_bytes = (size_t)NLEVELS * (size_t)B * 4;
    const size_t ws_needed = slab_bytes + HASH16_BYTES + DENSE_BYTES;

    if (ws_size >= ws_needed) {
        uint32_t* slab  = (uint32_t*)d_ws;
        uint32_t* tab16 = (uint32_t*)((char*)d_ws + slab_bytes);
        uint32_t* dense = (uint32_t*)((char*)d_ws + slab_bytes + HASH16_BYTES);

        // table prep
        hipLaunchKernelGGL(convert_hash_kernel,
                           dim3((HASH16_ENTRIES + BLOCK - 1) / BLOCK), dim3(BLOCK),
                           0, stream, emb, tab16);
        #define DBUILD(L) hipLaunchKernelGGL((dense_build_kernel<L>), \
            dim3((DRES(L)*DRES(L)*DRES(L) + BLOCK - 1) / BLOCK), dim3(BLOCK), 0, stream, emb, dense)
        DBUILD(0); DBUILD(1); DBUILD(2); DBUILD(3); DBUILD(4); DBUILD(5);
        #undef DBUILD

        // gathers, level-phased
        hipLaunchKernelGGL(dense_low_kernel, dim3(blocks2), dim3(BLOCK), 0, stream,
                           xyz, dense, mn, mx, slab, B);
        hipLaunchKernelGGL(dense_l5_kernel, dim3(blocks2), dim3(BLOCK), 0, stream,
                           xyz, dense, mn, mx, slab, B);
        #define HLVL(L, R) hipLaunchKernelGGL((hash_level_kernel<L, R>), dim3(blocks2), dim3(BLOCK), 0, stream, xyz, tab16, mn, mx, slab, B)
        HLVL(6, 111);  HLVL(7, 154);  HLVL(8, 212);  HLVL(9, 294);
        HLVL(10, 406); HLVL(11, 561); HLVL(12, 776); HLVL(13, 1072);
        HLVL(14, 1482); HLVL(15, 2048);
        #undef HLVL

        hipLaunchKernelGGL(transpose_kernel, dim3(blocks1), dim3(BLOCK), 0, stream,
                           slab, out, B);
    } else {
        hipLaunchKernelGGL(hashgrid_fused_kernel, dim3(blocks1), dim3(BLOCK), 0, stream,
                           xyz, emb, mn, mx, out, B);
    }
}

// Round 8
// 313.700 us; speedup vs baseline: 1.4955x; 1.2356x over previous
//
#include <hip/hip_runtime.h>
#include <hip/hip_fp16.h>
#include <stdint.h>

#define NLEVELS 16
#define BLOCK 256
#define NPT 2

#define P1 2654435761u
#define P2 805459861u
#define HMASK 0x7FFFFu

// dense tables for levels 0..5 (r^3 <= 2^19): entry = f16x2 packed in u32
__device__ __host__ constexpr int DRES(int l) {
    constexpr int r[6] = {16, 22, 30, 42, 58, 80};
    return r[l];
}
__device__ __host__ constexpr uint32_t DOFF(int l) {
    constexpr uint32_t o[7] = {0, 4096, 14744, 41744, 115832, 310944, 822944};
    return o[l];
}
#define DENSE_ENTRIES 822944u                       // sum of r^3, l=0..5
#define HASH16_ENTRIES (10u << 19)                  // levels 6..15
#define HASH16_BYTES ((size_t)HASH16_ENTRIES * 4)
#define DENSE_BYTES  ((size_t)DENSE_ENTRIES * 4)
#define PREP_TOTAL   (HASH16_ENTRIES + DENSE_ENTRIES)

// ---------------- one-time table prep: convert + dense builds, ONE dispatch ----------------
__global__ __launch_bounds__(BLOCK) void prep_kernel(
    const float* __restrict__ emb,
    uint32_t* __restrict__ tab16,
    uint32_t* __restrict__ dense)
{
    const uint32_t i = blockIdx.x * BLOCK + threadIdx.x;
    if (i < HASH16_ENTRIES) {
        // f32 hash table levels 6..15 -> f16x2
        const float2 v = *reinterpret_cast<const float2*>(
            emb + (((size_t)(6u << 19)) + i) * 2);
        __half2 hv = __floats2half2_rn(v.x, v.y);
        __builtin_nontemporal_store(*reinterpret_cast<uint32_t*>(&hv), &tab16[i]);
    } else if (i < PREP_TOTAL) {
        // dense re-index for levels 0..5: dense[x + y*r + z*r^2] = emb[hash(x,y,z)]
        const uint32_t j = i - HASH16_ENTRIES;
        int l = 0;
        #pragma unroll
        for (int q = 1; q < 6; ++q) if (j >= DOFF(q)) l = q;
        const int r = DRES(l);
        const uint32_t rel = j - DOFF(l);
        const int z = rel / (uint32_t)(r * r);
        const uint32_t rem = rel - (uint32_t)z * (uint32_t)(r * r);
        const int y = rem / (uint32_t)r;
        const int x = rem - (uint32_t)y * (uint32_t)r;
        const uint32_t h = ((uint32_t)x ^ ((uint32_t)y * P1) ^ ((uint32_t)z * P2)) & HMASK;
        const float2 v = *reinterpret_cast<const float2*>(
            emb + (((size_t)l << 19) + h) * 2);
        __half2 hv = __floats2half2_rn(v.x, v.y);
        dense[j] = *reinterpret_cast<uint32_t*>(&hv);
    }
}

// ---------------- shared helpers ----------------

struct PointCtx { float nx, ny, nz; bool valid; };

__device__ __forceinline__ PointCtx make_ctx(const float* __restrict__ xyz, int pt, int B,
                                             float mn0, float mn1, float mn2,
                                             float inv0, float inv1, float inv2)
{
    PointCtx P;
    P.nx = P.ny = P.nz = 0.0f;
    P.valid = false;
    if (pt < B) {
        const float x = xyz[3 * pt + 0];
        const float y = xyz[3 * pt + 1];
        const float z = xyz[3 * pt + 2];
        P.nx = (x - mn0) * inv0;
        P.ny = (y - mn1) * inv1;
        P.nz = (z - mn2) * inv2;
        P.valid = (P.nx >= 0.0f) && (P.nx <= 1.0f) &&
                  (P.ny >= 0.0f) && (P.ny <= 1.0f) &&
                  (P.nz >= 0.0f) && (P.nz <= 1.0f);
    }
    return P;
}

struct C8 { uint32_t idx[8]; float w[8]; };

__device__ __forceinline__ void frac_setup(const PointCtx& P, int r,
                                           int& fx, int& fy, int& fz,
                                           float& wx0, float& wx1,
                                           float& wy0, float& wy1,
                                           float& wz0, float& wz1)
{
    const float rm1 = (float)(r - 1);
    const float px = P.nx * rm1, py = P.ny * rm1, pz = P.nz * rm1;
    fx = (int)floorf(px); fx = min(max(fx, 0), r - 2);
    fy = (int)floorf(py); fy = min(max(fy, 0), r - 2);
    fz = (int)floorf(pz); fz = min(max(fz, 0), r - 2);
    wx1 = px - (float)fx; wx0 = 1.0f - wx1;
    wy1 = py - (float)fy; wy0 = 1.0f - wy1;
    wz1 = pz - (float)fz; wz0 = 1.0f - wz1;
}

__device__ __forceinline__ C8 mk_hash(const PointCtx& P, int r)
{
    int fx, fy, fz; float wx0, wx1, wy0, wy1, wz0, wz1;
    frac_setup(P, r, fx, fy, fz, wx0, wx1, wy0, wy1, wz0, wz1);
    const uint32_t hx0 = (uint32_t)fx,        hx1 = hx0 + 1u;
    const uint32_t hy0 = (uint32_t)fy * P1,   hy1 = hy0 + P1;
    const uint32_t hz0 = (uint32_t)fz * P2,   hz1 = hz0 + P2;
    C8 c;
    #pragma unroll
    for (int k = 0; k < 8; ++k) {
        c.idx[k] = (((k & 1) ? hx1 : hx0) ^
                    ((k & 2) ? hy1 : hy0) ^
                    ((k & 4) ? hz1 : hz0)) & HMASK;
        c.w[k] = ((k & 1) ? wx1 : wx0) * ((k & 2) ? wy1 : wy0) * ((k & 4) ? wz1 : wz0);
    }
    return c;
}

__device__ __forceinline__ C8 mk_dense(const PointCtx& P, int r, uint32_t off)
{
    int fx, fy, fz; float wx0, wx1, wy0, wy1, wz0, wz1;
    frac_setup(P, r, fx, fy, fz, wx0, wx1, wy0, wy1, wz0, wz1);
    const uint32_t base = off + (uint32_t)(fx + fy * r + fz * r * r);
    C8 c;
    #pragma unroll
    for (int k = 0; k < 8; ++k) {
        c.idx[k] = base + (uint32_t)((k & 1) + ((k & 2) ? r : 0) + ((k & 4) ? r * r : 0));
        c.w[k] = ((k & 1) ? wx1 : wx0) * ((k & 2) ? wy1 : wy0) * ((k & 4) ? wz1 : wz0);
    }
    return c;
}

__device__ __forceinline__ float2 accum8(const C8& c, const uint32_t* e, bool valid)
{
    float a = 0.0f, b = 0.0f;
    #pragma unroll
    for (int k = 0; k < 8; ++k) {
        const float2 f = __half22float2(*reinterpret_cast<const __half2*>(&e[k]));
        a = fmaf(c.w[k], f.x, a);
        b = fmaf(c.w[k], f.y, b);
    }
    float2 o;
    o.x = valid ? a : 0.0f;
    o.y = valid ? b : 0.0f;
    return o;
}

__device__ __forceinline__ void nt_store_f2h(uint32_t* p, float2 v)
{
    __half2 h = __floats2half2_rn(v.x, v.y);
    __builtin_nontemporal_store(*reinterpret_cast<uint32_t*>(&h), p);
}

// ---------------- mega gather: 12 level-major segments in ONE dispatch ----------------
// seg 0       : dense levels 0-4 (NPT points x 5 levels)
// seg 1       : dense level 5
// seg 2..11   : hash levels 6..15
__global__ __launch_bounds__(BLOCK, 4) void gather_mega_kernel(
    const float* __restrict__ xyz,
    const uint32_t* __restrict__ tab16,
    const uint32_t* __restrict__ dense,
    const float* __restrict__ minv,
    const float* __restrict__ maxv,
    uint32_t* __restrict__ slab,
    int B, int blocks2)
{
    constexpr int HRES[10] = {111, 154, 212, 294, 406, 561, 776, 1072, 1482, 2048};

    const int seg = blockIdx.x / blocks2;
    const int blk = blockIdx.x - seg * blocks2;

    const int t = threadIdx.x;
    const int p0 = blk * (NPT * BLOCK) + t;
    const int p1 = p0 + BLOCK;

    const float mn0 = minv[0], mn1 = minv[1], mn2 = minv[2];
    const float inv0 = 1.0f / (maxv[0] - mn0);
    const float inv1 = 1.0f / (maxv[1] - mn1);
    const float inv2 = 1.0f / (maxv[2] - mn2);

    const PointCtx A  = make_ctx(xyz, p0, B, mn0, mn1, mn2, inv0, inv1, inv2);
    const PointCtx Bc = make_ctx(xyz, p1, B, mn0, mn1, mn2, inv0, inv1, inv2);

    if (seg == 0) {
        #pragma unroll
        for (int l = 0; l < 5; ++l) {
            const C8 c0 = mk_dense(A,  DRES(l), DOFF(l));
            const C8 c1 = mk_dense(Bc, DRES(l), DOFF(l));
            uint32_t e0[8], e1[8];
            #pragma unroll
            for (int k = 0; k < 8; ++k) e0[k] = dense[c0.idx[k]];
            #pragma unroll
            for (int k = 0; k < 8; ++k) e1[k] = dense[c1.idx[k]];
            const float2 o0 = accum8(c0, e0, A.valid);
            const float2 o1 = accum8(c1, e1, Bc.valid);
            if (p0 < B) nt_store_f2h(&slab[(size_t)l * B + p0], o0);
            if (p1 < B) nt_store_f2h(&slab[(size_t)l * B + p1], o1);
        }
    } else if (seg == 1) {
        const C8 c0 = mk_dense(A,  DRES(5), DOFF(5));
        const C8 c1 = mk_dense(Bc, DRES(5), DOFF(5));
        uint32_t e0[8], e1[8];
        #pragma unroll
        for (int k = 0; k < 8; ++k) e0[k] = dense[c0.idx[k]];
        #pragma unroll
        for (int k = 0; k < 8; ++k) e1[k] = dense[c1.idx[k]];
        const float2 o0 = accum8(c0, e0, A.valid);
        const float2 o1 = accum8(c1, e1, Bc.valid);
        if (p0 < B) nt_store_f2h(&slab[(size_t)5 * B + p0], o0);
        if (p1 < B) nt_store_f2h(&slab[(size_t)5 * B + p1], o1);
    } else {
        const int l = seg + 4;                    // 6..15
        const int r = HRES[seg - 2];
        const uint32_t* __restrict__ lt = tab16 + ((size_t)(l - 6) << 19);
        const C8 c0 = mk_hash(A,  r);
        const C8 c1 = mk_hash(Bc, r);
        uint32_t e0[8], e1[8];
        #pragma unroll
        for (int k = 0; k < 8; ++k) e0[k] = lt[c0.idx[k]];
        #pragma unroll
        for (int k = 0; k < 8; ++k) e1[k] = lt[c1.idx[k]];
        const float2 o0 = accum8(c0, e0, A.valid);
        const float2 o1 = accum8(c1, e1, Bc.valid);
        if (p0 < B) nt_store_f2h(&slab[(size_t)l * B + p0], o0);
        if (p1 < B) nt_store_f2h(&slab[(size_t)l * B + p1], o1);
    }
}

// ---------------- final transpose: slab[16][B] (f16x2) -> out[B][32] (f32) ----------------
__global__ __launch_bounds__(BLOCK) void transpose_kernel(
    const uint32_t* __restrict__ slab,
    float* __restrict__ out,
    int B)
{
    __shared__ float s[32][BLOCK + 1];
    const int t = threadIdx.x;
    const int pt = blockIdx.x * BLOCK + t;

    #pragma unroll
    for (int l = 0; l < NLEVELS; ++l) {
        float2 v = make_float2(0.0f, 0.0f);
        if (pt < B) {
            const uint32_t bits = __builtin_nontemporal_load(&slab[(size_t)l * B + pt]);
            v = __half22float2(*reinterpret_cast<const __half2*>(&bits));
        }
        s[2 * l + 0][t] = v.x;
        s[2 * l + 1][t] = v.y;
    }
    __syncthreads();

    const size_t chunk = (size_t)blockIdx.x * (BLOCK * 32);
    const size_t total = (size_t)B * 32;
    #pragma unroll
    for (int k = 0; k < 32; ++k) {
        const int flat = k * BLOCK + t;
        const int p = flat >> 5;
        const int c = flat & 31;
        const size_t g = chunk + (size_t)flat;
        if (g < total) __builtin_nontemporal_store(s[c][p], &out[g]);
    }
}

// ---------------- fallback: single fused f32 kernel ----------------
__global__ __launch_bounds__(BLOCK) void hashgrid_fused_kernel(
    const float* __restrict__ xyz,
    const float* __restrict__ emb,
    const float* __restrict__ minv,
    const float* __restrict__ maxv,
    float* __restrict__ out,
    int B)
{
    constexpr int RES[NLEVELS] = {16, 22, 30, 42, 58, 80, 111, 154,
                                  212, 294, 406, 561, 776, 1072, 1482, 2048};
    __shared__ float s[32][BLOCK + 1];
    const int t = threadIdx.x;
    const int pt = blockIdx.x * BLOCK + t;

    const float mn0 = minv[0], mn1 = minv[1], mn2 = minv[2];
    const float inv0 = 1.0f / (maxv[0] - mn0);
    const float inv1 = 1.0f / (maxv[1] - mn1);
    const float inv2 = 1.0f / (maxv[2] - mn2);

    const PointCtx P = make_ctx(xyz, pt, B, mn0, mn1, mn2, inv0, inv1, inv2);

    #pragma unroll
    for (int l = 0; l < NLEVELS; ++l) {
        const C8 c = mk_hash(P, RES[l]);
        const float* __restrict__ lemb = emb + ((size_t)l << 20);
        float acc0 = 0.0f, acc1 = 0.0f;
        #pragma unroll
        for (int k = 0; k < 8; ++k) {
            const float2 f = *reinterpret_cast<const float2*>(
                lemb + ((size_t)c.idx[k] << 1));
            acc0 = fmaf(c.w[k], f.x, acc0);
            acc1 = fmaf(c.w[k], f.y, acc1);
        }
        s[2 * l + 0][t] = P.valid ? acc0 : 0.0f;
        s[2 * l + 1][t] = P.valid ? acc1 : 0.0f;
    }
    __syncthreads();
    const size_t chunk = (size_t)blockIdx.x * (BLOCK * 32);
    const size_t total = (size_t)B * 32;
    #pragma unroll
    for (int k = 0; k < 32; ++k) {
        const int flat = k * BLOCK + t;
        const int p = flat >> 5;
        const int c = flat & 31;
        const size_t g = chunk + (size_t)flat;
        if (g < total) out[g] = s[c][p];
    }
}

extern "C" void kernel_launch(void* const* d_in, const int* in_sizes, int n_in,
                              void* d_out, int out_size, void* d_ws, size_t ws_size,
                              hipStream_t stream) {
    const float* xyz = (const float*)d_in[0];
    const float* emb = (const float*)d_in[1];
    const float* mn  = (const float*)d_in[2];
    const float* mx  = (const float*)d_in[3];
    float* out = (float*)d_out;

    const int B = in_sizes[0] / 3;
    const int blocks1 = (B + BLOCK - 1) / BLOCK;
    const int blocks2 = (B + NPT * BLOCK - 1) / (NPT * BLOCK);

    const size_t slab_bytes = (size_t)NLEVELS * (size_t)B * 4;
    const size_t ws_needed = slab_bytes + HASH16_BYTES + DENSE_BYTES;

    if (ws_size >= ws_needed) {
        uint32_t* slab  = (uint32_t*)d_ws;
        uint32_t* tab16 = (uint32_t*)((char*)d_ws + slab_bytes);
        uint32_t* dense = (uint32_t*)((char*)d_ws + slab_bytes + HASH16_BYTES);

        hipLaunchKernelGGL(prep_kernel,
                           dim3((PREP_TOTAL + BLOCK - 1) / BLOCK), dim3(BLOCK),
                           0, stream, emb, tab16, dense);

        hipLaunchKernelGGL(gather_mega_kernel, dim3(12 * blocks2), dim3(BLOCK), 0, stream,
                           xyz, tab16, dense, mn, mx, slab, B, blocks2);

        hipLaunchKernelGGL(transpose_kernel, dim3(blocks1), dim3(BLOCK), 0, stream,
                           slab, out, B);
    } else {
        hipLaunchKernelGGL(hashgrid_fused_kernel, dim3(blocks1), dim3(BLOCK), 0, stream,
                           xyz, emb, mn, mx, out, B);
    }
}